// Round 1
// baseline (1536.463 us; speedup 1.0000x reference)
//
#include <hip/hip_runtime.h>
#include <math.h>

constexpr int Bc  = 4;
constexpr int Nc  = 2304;
constexpr int KSc = 8;
constexpr int Cc  = 512;
constexpr int Hc  = 8;
constexpr int Dc  = 64;
constexpr int NTc = Nc + KSc;          // 2312
constexpr int M1c = Bc * NTc;          // 9248
constexpr int N1c = 3 * Cc;            // 1536
constexpr int M2c = Bc * Nc;           // 9216
constexpr int QTILES = Nc / 64;        // 36 (exact)
constexpr int KTILES = (NTc + 63) / 64;// 37 (last tile = 8 keys)

// ---------------------------------------------------------------------------
// Tiled fp32 GEMM: C[M,Ncols] = A[M,512] * B[512,Ncols]
// MODE 0: A = concat(X_flat, S_tokens) rows; epilogue scatters to Q/K/V in
//         (B,H,Nt,D) layout.
// MODE 1: A = Oattn (row-major, stride 512); epilogue stores to Outp.
// 128x128 tile, BK=8, 256 threads, 8x8 per thread.
// ---------------------------------------------------------------------------
template<int MODE>
__global__ __launch_bounds__(256)
void gemm_fp32(const float* __restrict__ A0, const float* __restrict__ A1,
               const float* __restrict__ Bm,
               float* __restrict__ Qb, float* __restrict__ Kb, float* __restrict__ Vb,
               float* __restrict__ Outp, int Mrows, int Ncols)
{
    __shared__ float As[8][128];   // transposed A tile: As[k][m]
    __shared__ float Bs[8][128];

    const int tid = threadIdx.x;
    const int tx = tid & 15;
    const int ty = tid >> 4;
    const int m0 = blockIdx.x * 128;
    const int n0 = blockIdx.y * 128;

    float acc[8][8];
#pragma unroll
    for (int i = 0; i < 8; ++i)
#pragma unroll
        for (int j = 0; j < 8; ++j) acc[i][j] = 0.f;

    // A-tile load coords: 128 rows x 8 k, float4 per thread
    const int la_row = tid >> 1;          // 0..127
    const int la_k   = (tid & 1) * 4;     // 0 or 4
    int arow = m0 + la_row;
    if (arow > Mrows - 1) arow = Mrows - 1;
    const float* Arow;
    if (MODE == 0) {
        const int b = arow / NTc;
        const int t = arow - b * NTc;
        Arow = (t < Nc) ? (A0 + (size_t)(b * Nc + t) * Cc)
                        : (A1 + (size_t)(b * KSc + (t - Nc)) * Cc);
    } else {
        Arow = A0 + (size_t)arow * Cc;
    }

    // B-tile load coords: 8 rows x 128 cols, float4 per thread
    const int lb_row = tid >> 5;          // 0..7
    const int lb_col = (tid & 31) * 4;    // 0..124
    const float* Bp = Bm + (size_t)lb_row * Ncols + n0 + lb_col;

    for (int k0 = 0; k0 < Cc; k0 += 8) {
        const float4 av = *(const float4*)(Arow + k0 + la_k);
        const float4 bv = *(const float4*)(Bp + (size_t)k0 * Ncols);
        __syncthreads();
        As[la_k + 0][la_row] = av.x;
        As[la_k + 1][la_row] = av.y;
        As[la_k + 2][la_row] = av.z;
        As[la_k + 3][la_row] = av.w;
        *(float4*)&Bs[lb_row][lb_col] = bv;
        __syncthreads();
#pragma unroll
        for (int kk = 0; kk < 8; ++kk) {
            float a[8], b[8];
            *(float4*)&a[0] = *(const float4*)&As[kk][ty * 8];
            *(float4*)&a[4] = *(const float4*)&As[kk][ty * 8 + 4];
            *(float4*)&b[0] = *(const float4*)&Bs[kk][tx * 4];
            *(float4*)&b[4] = *(const float4*)&Bs[kk][64 + tx * 4];
#pragma unroll
            for (int i = 0; i < 8; ++i)
#pragma unroll
                for (int j = 0; j < 8; ++j)
                    acc[i][j] = fmaf(a[i], b[j], acc[i][j]);
        }
    }

#pragma unroll
    for (int i = 0; i < 8; ++i) {
        const int row = m0 + ty * 8 + i;
        if (row >= Mrows) break;
        const float4 v0 = make_float4(acc[i][0], acc[i][1], acc[i][2], acc[i][3]);
        const float4 v1 = make_float4(acc[i][4], acc[i][5], acc[i][6], acc[i][7]);
        if (MODE == 1) {
            float* op = Outp + (size_t)row * Ncols + n0;
            *(float4*)(op + tx * 4)      = v0;
            *(float4*)(op + 64 + tx * 4) = v1;
        } else {
            const int b = row / NTc;
            const int t = row - b * NTc;
            {
                const int col   = n0 + tx * 4;
                const int which = col >> 9;
                const int h     = (col >> 6) & 7;
                const int d     = col & 63;
                float* base = (which == 0) ? Qb : (which == 1 ? Kb : Vb);
                *(float4*)(base + ((size_t)((b * Hc + h) * NTc + t)) * Dc + d) = v0;
            }
            {
                const int col   = n0 + 64 + tx * 4;
                const int which = col >> 9;
                const int h     = (col >> 6) & 7;
                const int d     = col & 63;
                float* base = (which == 0) ? Qb : (which == 1 ? Kb : Vb);
                *(float4*)(base + ((size_t)((b * Hc + h) * NTc + t)) * Dc + d) = v1;
            }
        }
    }
}

// ---------------------------------------------------------------------------
// L2-normalize q,k rows (D=64) in place; fold temperature[h] into q.
// One 64-lane group per row, 4 rows per 256-thread block.
// ---------------------------------------------------------------------------
__global__ __launch_bounds__(256)
void norm_kernel(float* __restrict__ Qb, float* __restrict__ Kb,
                 const float* __restrict__ temp)
{
    const int r = blockIdx.x * 4 + (threadIdx.x >> 6);
    const int lane = threadIdx.x & 63;
    if (r >= Bc * Hc * NTc) return;
    const int h = (r / NTc) & (Hc - 1);   // r = (b*H+h)*NT + t

    const size_t idx = (size_t)r * Dc + lane;
    float q = Qb[idx];
    float k = Kb[idx];
    float qs = q * q, ks = k * k;
#pragma unroll
    for (int m = 1; m < 64; m <<= 1) {
        qs += __shfl_xor(qs, m);
        ks += __shfl_xor(ks, m);
    }
    const float tscale = temp[h];
    const float qn = tscale / fmaxf(sqrtf(qs), 1e-12f);
    const float kn = 1.0f   / fmaxf(sqrtf(ks), 1e-12f);
    Qb[idx] = q * qn;
    Kb[idx] = k * kn;
}

// ---------------------------------------------------------------------------
// Flash-style attention, fp32. Block = 256 threads = 64 queries x 4 lanes.
// Each lane owns 16 of the 64 D-components of its query. K/V tiles of 64
// keys staged in LDS. Online softmax with rare-rescale branch. Only the
// first N=2304 queries are computed (rows >= N are sliced away by the ref).
// Writes Oattn in (B, N, C) layout (C index = h*64 + d).
// ---------------------------------------------------------------------------
__global__ __launch_bounds__(256)
void attn_kernel(const float* __restrict__ Qb, const float* __restrict__ Kb,
                 const float* __restrict__ Vb, float* __restrict__ Oa)
{
    __shared__ float Ks[64][64];
    __shared__ float Vs[64][64];

    const int tid   = threadIdx.x;
    const int bh    = blockIdx.x / QTILES;   // 0..31
    const int qtile = blockIdx.x % QTILES;
    const int b     = bh >> 3;
    const int h     = bh & 7;
    const int qloc  = tid >> 2;              // 0..63
    const int part  = tid & 3;               // 0..3
    const int qi    = qtile * 64 + qloc;     // < N

    const float* Qp = Qb + ((size_t)bh * NTc + qi) * Dc + part * 16;
    float qr[16];
    *(float4*)&qr[0]  = *(const float4*)(Qp + 0);
    *(float4*)&qr[4]  = *(const float4*)(Qp + 4);
    *(float4*)&qr[8]  = *(const float4*)(Qp + 8);
    *(float4*)&qr[12] = *(const float4*)(Qp + 12);

    float oa[16];
#pragma unroll
    for (int c = 0; c < 16; ++c) oa[c] = 0.f;
    float mrun = -INFINITY;
    float lrun = 0.f;

    const float* Kbase = Kb + (size_t)bh * NTc * Dc;
    const float* Vbase = Vb + (size_t)bh * NTc * Dc;

    for (int kt = 0; kt < KTILES; ++kt) {
        const int kbase = kt * 64;
        __syncthreads();
        // stage 64 keys + 64 values (16 KiB each), coalesced float4
#pragma unroll
        for (int jj = 0; jj < 4; ++jj) {
            const int f4  = jj * 256 + tid;      // float4 index 0..1023
            const int row = f4 >> 4;
            const int col = (f4 & 15) * 4;
            int rg = kbase + row;
            if (rg > NTc - 1) rg = NTc - 1;
            *(float4*)&Ks[row][col] = *(const float4*)(Kbase + (size_t)rg * Dc + col);
            *(float4*)&Vs[row][col] = *(const float4*)(Vbase + (size_t)rg * Dc + col);
        }
        __syncthreads();

        int jmax = NTc - kbase;
        if (jmax > 64) jmax = 64;
        for (int j = 0; j < jmax; ++j) {
            float kf[16];
            const float* kr = &Ks[j][part * 16];
            *(float4*)&kf[0]  = *(const float4*)(kr + 0);
            *(float4*)&kf[4]  = *(const float4*)(kr + 4);
            *(float4*)&kf[8]  = *(const float4*)(kr + 8);
            *(float4*)&kf[12] = *(const float4*)(kr + 12);
            float s = 0.f;
#pragma unroll
            for (int c = 0; c < 16; ++c) s = fmaf(qr[c], kf[c], s);
            s += __shfl_xor(s, 1);
            s += __shfl_xor(s, 2);   // full q.k (temperature pre-folded into q)

            if (s > mrun) {
                const float corr = __expf(mrun - s);   // 0 on first key
                lrun *= corr;
#pragma unroll
                for (int c = 0; c < 16; ++c) oa[c] *= corr;
                mrun = s;
            }
            const float p = __expf(s - mrun);
            lrun += p;

            float vf[16];
            const float* vr = &Vs[j][part * 16];
            *(float4*)&vf[0]  = *(const float4*)(vr + 0);
            *(float4*)&vf[4]  = *(const float4*)(vr + 4);
            *(float4*)&vf[8]  = *(const float4*)(vr + 8);
            *(float4*)&vf[12] = *(const float4*)(vr + 12);
#pragma unroll
            for (int c = 0; c < 16; ++c) oa[c] = fmaf(p, vf[c], oa[c]);
        }
    }

    const float inv = 1.0f / lrun;
    float* Op = Oa + ((size_t)(b * Nc + qi)) * Cc + h * Dc + part * 16;
    float4 s0 = make_float4(oa[0] * inv,  oa[1] * inv,  oa[2] * inv,  oa[3] * inv);
    float4 s1 = make_float4(oa[4] * inv,  oa[5] * inv,  oa[6] * inv,  oa[7] * inv);
    float4 s2 = make_float4(oa[8] * inv,  oa[9] * inv,  oa[10] * inv, oa[11] * inv);
    float4 s3 = make_float4(oa[12] * inv, oa[13] * inv, oa[14] * inv, oa[15] * inv);
    *(float4*)(Op + 0)  = s0;
    *(float4*)(Op + 4)  = s1;
    *(float4*)(Op + 8)  = s2;
    *(float4*)(Op + 12) = s3;
}

// ---------------------------------------------------------------------------
extern "C" void kernel_launch(void* const* d_in, const int* in_sizes, int n_in,
                              void* d_out, int out_size, void* d_ws, size_t ws_size,
                              hipStream_t stream)
{
    const float* X    = (const float*)d_in[0];
    const float* S    = (const float*)d_in[1];
    const float* Wqkv = (const float*)d_in[2];
    const float* Wout = (const float*)d_in[3];
    const float* temp = (const float*)d_in[4];
    float* out = (float*)d_out;

    float* ws = (float*)d_ws;
    const size_t R = (size_t)Bc * Hc * NTc * Dc;  // 4,734,976 floats per buffer
    float* Qb = ws;
    float* Kb = ws + R;
    float* Vb = ws + 2 * R;
    float* Oa = ws + 3 * R;                       // B*N*C = 4,718,592 floats

    // 1) QKV GEMM with fused concat + scatter to (B,H,Nt,D)
    dim3 g1((M1c + 127) / 128, N1c / 128);        // 73 x 12
    gemm_fp32<0><<<g1, 256, 0, stream>>>(X, S, Wqkv, Qb, Kb, Vb, nullptr, M1c, N1c);

    // 2) L2-normalize q,k (+ fold temperature into q)
    norm_kernel<<<(Bc * Hc * NTc) / 4, 256, 0, stream>>>(Qb, Kb, temp);

    // 3) Flash attention (first N queries only) -> Oattn (B,N,C)
    attn_kernel<<<Bc * Hc * QTILES, 256, 0, stream>>>(Qb, Kb, Vb, Oa);

    // 4) Output GEMM: Oattn @ Wout -> d_out
    dim3 g2(M2c / 128, Cc / 128);                 // 72 x 4
    gemm_fp32<1><<<g2, 256, 0, stream>>>(Oa, nullptr, Wout, nullptr, nullptr, nullptr, out, M2c, Cc);
}

// Round 3
// 418.205 us; speedup vs baseline: 3.6739x; 3.6739x over previous
//
#include <hip/hip_runtime.h>
#include <math.h>

typedef unsigned short u16;
typedef unsigned int   u32;
typedef __attribute__((ext_vector_type(8)))  __bf16 bf16x8;
typedef __attribute__((ext_vector_type(16))) float  f32x16;

constexpr int Bc  = 4;
constexpr int Nc  = 2304;
constexpr int KSc = 8;
constexpr int Cc  = 512;
constexpr int Hc  = 8;
constexpr int Dc  = 64;
constexpr int NTc = Nc + KSc;          // 2312
constexpr int M1c = Bc * NTc;          // 9248
constexpr int N1c = 3 * Cc;            // 1536
constexpr int M2c = Bc * Nc;           // 9216
constexpr int QT128 = Nc / 128;        // 18 query tiles of 128
constexpr int KT64  = NTc / 64;        // 36 full 64-key tiles (+8 tail)

__device__ __forceinline__ u32 f2bf1(float f) {
    u32 u = __float_as_uint(f);
    return (u + 0x7fffu + ((u >> 16) & 1u)) >> 16;   // RNE bf16
}
__device__ __forceinline__ u32 pk2(float lo, float hi) {
    u32 ul = __float_as_uint(lo);
    u32 uh = __float_as_uint(hi);
    ul = (ul + 0x7fffu + ((ul >> 16) & 1u)) >> 16;
    uh = (uh + 0x7fffu + ((uh >> 16) & 1u)) & 0xffff0000u;
    return ul | uh;
}

#define MFMA32(A, B, C) __builtin_amdgcn_mfma_f32_32x32x16_bf16(A, B, C, 0, 0, 0)

union U4 { u32 u[4]; bf16x8 f; };

// ---------------------------------------------------------------------------
// Tiled fp32 GEMM. MODE 0: QKV with fused concat; epilogue scatters Q,K as
// f32 (B,H,Nt,D) and V as bf16 TRANSPOSED (B,H,D,Nt). MODE 1: plain store.
// ---------------------------------------------------------------------------
template<int MODE>
__global__ __launch_bounds__(256)
void gemm_fp32(const float* __restrict__ A0, const float* __restrict__ A1,
               const float* __restrict__ Bm,
               float* __restrict__ Qb, float* __restrict__ Kb, u16* __restrict__ Vt,
               float* __restrict__ Outp, int Mrows, int Ncols)
{
    __shared__ float As[8][128];
    __shared__ float Bs[8][128];

    const int tid = threadIdx.x;
    const int tx = tid & 15;
    const int ty = tid >> 4;
    const int m0 = blockIdx.x * 128;
    const int n0 = blockIdx.y * 128;

    float acc[8][8];
#pragma unroll
    for (int i = 0; i < 8; ++i)
#pragma unroll
        for (int j = 0; j < 8; ++j) acc[i][j] = 0.f;

    const int la_row = tid >> 1;
    const int la_k   = (tid & 1) * 4;
    int arow = m0 + la_row;
    if (arow > Mrows - 1) arow = Mrows - 1;
    const float* Arow;
    if (MODE == 0) {
        const int b = arow / NTc;
        const int t = arow - b * NTc;
        Arow = (t < Nc) ? (A0 + (size_t)(b * Nc + t) * Cc)
                        : (A1 + (size_t)(b * KSc + (t - Nc)) * Cc);
    } else {
        Arow = A0 + (size_t)arow * Cc;
    }

    const int lb_row = tid >> 5;
    const int lb_col = (tid & 31) * 4;
    const float* Bp = Bm + (size_t)lb_row * Ncols + n0 + lb_col;

    for (int k0 = 0; k0 < Cc; k0 += 8) {
        const float4 av = *(const float4*)(Arow + k0 + la_k);
        const float4 bv = *(const float4*)(Bp + (size_t)k0 * Ncols);
        __syncthreads();
        As[la_k + 0][la_row] = av.x;
        As[la_k + 1][la_row] = av.y;
        As[la_k + 2][la_row] = av.z;
        As[la_k + 3][la_row] = av.w;
        *(float4*)&Bs[lb_row][lb_col] = bv;
        __syncthreads();
#pragma unroll
        for (int kk = 0; kk < 8; ++kk) {
            float a[8], b[8];
            *(float4*)&a[0] = *(const float4*)&As[kk][ty * 8];
            *(float4*)&a[4] = *(const float4*)&As[kk][ty * 8 + 4];
            *(float4*)&b[0] = *(const float4*)&Bs[kk][tx * 4];
            *(float4*)&b[4] = *(const float4*)&Bs[kk][64 + tx * 4];
#pragma unroll
            for (int i = 0; i < 8; ++i)
#pragma unroll
                for (int j = 0; j < 8; ++j)
                    acc[i][j] = fmaf(a[i], b[j], acc[i][j]);
        }
    }

#pragma unroll
    for (int i = 0; i < 8; ++i) {
        const int row = m0 + ty * 8 + i;
        if (row >= Mrows) break;
        const float4 v0 = make_float4(acc[i][0], acc[i][1], acc[i][2], acc[i][3]);
        const float4 v1 = make_float4(acc[i][4], acc[i][5], acc[i][6], acc[i][7]);
        if (MODE == 1) {
            float* op = Outp + (size_t)row * Ncols + n0;
            *(float4*)(op + tx * 4)      = v0;
            *(float4*)(op + 64 + tx * 4) = v1;
        } else {
            const int b = row / NTc;
            const int t = row - b * NTc;
#pragma unroll
            for (int half = 0; half < 2; ++half) {
                const float4 v = half ? v1 : v0;
                const int col  = n0 + half * 64 + tx * 4;
                const int which = col >> 9;
                const int h     = (col >> 6) & 7;
                const int d     = col & 63;
                if (which < 2) {
                    float* base = (which == 0) ? Qb : Kb;
                    *(float4*)(base + ((size_t)((b * Hc + h) * NTc + t)) * Dc + d) = v;
                } else {
                    u16* vp = Vt + ((size_t)((b * Hc + h) * Dc + d)) * NTc + t;
                    vp[0 * NTc] = (u16)f2bf1(v.x);
                    vp[1 * NTc] = (u16)f2bf1(v.y);
                    vp[2 * NTc] = (u16)f2bf1(v.z);
                    vp[3 * NTc] = (u16)f2bf1(v.w);
                }
            }
        }
    }
}

// ---------------------------------------------------------------------------
// L2-normalize q,k rows (D=64); fold temperature[h] into q; emit bf16.
// ---------------------------------------------------------------------------
__global__ __launch_bounds__(256)
void norm_kernel(const float* __restrict__ Qf, const float* __restrict__ Kf,
                 u16* __restrict__ Qbf, u16* __restrict__ Kbf,
                 const float* __restrict__ temp)
{
    const int r = blockIdx.x * 4 + (threadIdx.x >> 6);
    const int lane = threadIdx.x & 63;
    const int h = (r / NTc) & (Hc - 1);

    const size_t idx = (size_t)r * Dc + lane;
    float q = Qf[idx];
    float k = Kf[idx];
    float qs = q * q, ks = k * k;
#pragma unroll
    for (int m = 1; m < 64; m <<= 1) {
        qs += __shfl_xor(qs, m);
        ks += __shfl_xor(ks, m);
    }
    const float tscale = temp[h];
    const float qn = tscale / fmaxf(sqrtf(qs), 1e-12f);
    const float kn = 1.0f   / fmaxf(sqrtf(ks), 1e-12f);
    Qbf[idx] = (u16)f2bf1(q * qn);
    Kbf[idx] = (u16)f2bf1(k * kn);
}

// ---------------------------------------------------------------------------
// MFMA flash attention, bf16 inputs, fp32 accum. Block = 4 waves x 32 queries.
// Swapped QK^T: S^T = mfma(K, Q) -> lane holds P[16 keys][its query].
// Constant softmax shift m = |temp[h]| (logits bounded since q,k unit norm).
// PV: O^T = mfma(V^T, P). K/V^T tiles (64 keys) in XOR-swizzled LDS.
// ---------------------------------------------------------------------------
__global__ __launch_bounds__(256)
void attn_mfma(const u16* __restrict__ Qbf, const u16* __restrict__ Kbf,
               const u16* __restrict__ Vtg, const float* __restrict__ temp,
               float* __restrict__ Oa)
{
    __shared__ __align__(16) u16 ldsK[64 * 64];
    __shared__ __align__(16) u16 ldsV[64 * 64];

    const int tid  = threadIdx.x;
    const int wid  = tid >> 6;
    const int lane = tid & 63;
    const int hi   = lane >> 5;
    const int ln   = lane & 31;
    const int bh   = blockIdx.x / QT128;
    const int qt   = blockIdx.x - bh * QT128;
    const int b    = bh >> 3, h = bh & 7;
    const int qbase = qt * 128 + wid * 32;
    const float mconst = fabsf(temp[h]);

    // Q B-fragments (hoisted): B[k][q] = Q[qbase+ln][ks*16 + hi*8 + j]
    const u16* Qrow = Qbf + ((size_t)bh * NTc + qbase + ln) * Dc;
    bf16x8 qf[4];
#pragma unroll
    for (int ks = 0; ks < 4; ++ks)
        qf[ks] = *(const bf16x8*)(Qrow + ks * 16 + hi * 8);

    f32x16 o0, o1;
#pragma unroll
    for (int r = 0; r < 16; ++r) { o0[r] = 0.f; o1[r] = 0.f; }
    float rs = 0.f;

    const u16* Kbh = Kbf + (size_t)bh * NTc * Dc;
    const u16* Vbh = Vtg + (size_t)bh * Dc * NTc;

    // staging coords: chunk sc (16B) of rows sr0 and sr0+32  (full 8 KiB/tile)
    const int sc  = tid & 7;       // 0..7
    const int sr0 = tid >> 3;      // 0..31
    char* ldsKc = (char*)ldsK;
    char* ldsVc = (char*)ldsV;
    const int slot = (sc << 4) ^ ((sr0 & 7) << 4);   // (sr0+32)&7 == sr0&7

    for (int kt = 0; kt <= KT64; ++kt) {
        const int  kb   = kt * 64;
        const bool tail = (kt == KT64);   // last 8 keys
        __syncthreads();
#pragma unroll
        for (int half = 0; half < 2; ++half) {
            const int r   = sr0 + half * 32;
            const int wof = (r << 7) + slot;
            int rK = kb + r;
            if (rK > NTc - 1) rK = NTc - 1;            // tail: duplicate last row
            int cV = kb + sc * 8;
            if (cV > NTc - 8) cV = NTc - 8;            // tail: clamp columns
            *(uint4*)(ldsKc + wof) = *(const uint4*)(Kbh + (size_t)rK * Dc + sc * 8);
            *(uint4*)(ldsVc + wof) = *(const uint4*)(Vbh + (size_t)r * NTc + cV);
        }
        __syncthreads();

        const int nsub = tail ? 1 : 2;
        for (int kt2 = 0; kt2 < nsub; ++kt2) {
            f32x16 s;
#pragma unroll
            for (int r = 0; r < 16; ++r) s[r] = 0.f;
            const int krow = kt2 * 32 + ln;
            const char* kbc = ldsKc + (krow << 7);
            const int   ksz = (krow & 7) << 4;
#pragma unroll
            for (int ks = 0; ks < 4; ++ks) {
                const bf16x8 kf = *(const bf16x8*)(kbc + (((ks << 5) + (hi << 4)) ^ ksz));
                s = MFMA32(kf, qf[ks], s);
            }

            float p[16];
            if (!tail) {
#pragma unroll
                for (int r = 0; r < 16; ++r) p[r] = __expf(s[r] - mconst);
            } else {
                // valid keys: (r&3)+8*(r>>2)+4*hi < 8  <=>  r < 4 (both hi)
#pragma unroll
                for (int r = 0; r < 16; ++r) p[r] = (r < 4) ? __expf(s[r] - mconst) : 0.f;
            }
#pragma unroll
            for (int r = 0; r < 16; ++r) rs += p[r];

            // pack to bf16 pairs and exchange with partner lane (l ^ 32)
            const u32 a0 = pk2(p[0],  p[1]),  a1 = pk2(p[2],  p[3]);
            const u32 b0 = pk2(p[4],  p[5]),  b1 = pk2(p[6],  p[7]);
            const u32 c0 = pk2(p[8],  p[9]),  c1 = pk2(p[10], p[11]);
            const u32 d0 = pk2(p[12], p[13]), d1 = pk2(p[14], p[15]);
            const u32 xa0 = (u32)__shfl_xor((int)a0, 32);
            const u32 xa1 = (u32)__shfl_xor((int)a1, 32);
            const u32 xb0 = (u32)__shfl_xor((int)b0, 32);
            const u32 xb1 = (u32)__shfl_xor((int)b1, 32);
            const u32 xc0 = (u32)__shfl_xor((int)c0, 32);
            const u32 xc1 = (u32)__shfl_xor((int)c1, 32);
            const u32 xd0 = (u32)__shfl_xor((int)d0, 32);
            const u32 xd1 = (u32)__shfl_xor((int)d1, 32);
            U4 f0, f1;
            f0.u[0] = hi ? xb0 : a0;
            f0.u[1] = hi ? xb1 : a1;
            f0.u[2] = hi ? b0  : xa0;
            f0.u[3] = hi ? b1  : xa1;
            f1.u[0] = hi ? xd0 : c0;
            f1.u[1] = hi ? xd1 : c1;
            f1.u[2] = hi ? d0  : xc0;
            f1.u[3] = hi ? d1  : xc1;

            // PV: A = V^T rows (d), k = key slice
            const char* v0c = ldsVc + (ln << 7);
            const char* v1c = ldsVc + ((32 + ln) << 7);
            const int   vsz0 = (ln & 7) << 4;
            const int   cof0 = ((kt2 << 6) + (hi << 4)) ^ vsz0;        // kh = 0
            const int   cof1 = ((kt2 << 6) + 32 + (hi << 4)) ^ vsz0;   // kh = 1
            o0 = MFMA32(*(const bf16x8*)(v0c + cof0), f0.f, o0);
            o1 = MFMA32(*(const bf16x8*)(v1c + cof0), f0.f, o1);
            if (!tail) {
                o0 = MFMA32(*(const bf16x8*)(v0c + cof1), f1.f, o0);
                o1 = MFMA32(*(const bf16x8*)(v1c + cof1), f1.f, o1);
            }
        }
    }

    rs += __shfl_xor(rs, 32);
    const float inv = 1.0f / rs;
    float* Op = Oa + ((size_t)(b * Nc) + qbase + ln) * Cc + h * Dc;
#pragma unroll
    for (int g = 0; g < 4; ++g) {
        const float4 w0 = make_float4(o0[4*g] * inv, o0[4*g+1] * inv,
                                      o0[4*g+2] * inv, o0[4*g+3] * inv);
        const float4 w1 = make_float4(o1[4*g] * inv, o1[4*g+1] * inv,
                                      o1[4*g+2] * inv, o1[4*g+3] * inv);
        *(float4*)(Op + 8*g + 4*hi)      = w0;   // d = 8g + 4hi + {0..3}
        *(float4*)(Op + 32 + 8*g + 4*hi) = w1;
    }
}

// ---------------------------------------------------------------------------
extern "C" void kernel_launch(void* const* d_in, const int* in_sizes, int n_in,
                              void* d_out, int out_size, void* d_ws, size_t ws_size,
                              hipStream_t stream)
{
    const float* X    = (const float*)d_in[0];
    const float* S    = (const float*)d_in[1];
    const float* Wqkv = (const float*)d_in[2];
    const float* Wout = (const float*)d_in[3];
    const float* temp = (const float*)d_in[4];
    float* out = (float*)d_out;

    float* ws = (float*)d_ws;
    const size_t R = (size_t)Bc * Hc * NTc * Dc;   // 4,734,976
    float* Qf  = ws;               // f32 (B,H,Nt,D)   -- later reused as Oa
    float* Kf  = ws + R;           // f32 (B,H,Nt,D)
    u16*   Qbf = (u16*)(ws + 2 * R);
    u16*   Kbf = Qbf + R;
    u16*   Vtg = Kbf + R;          // bf16 (B,H,D,Nt)
    float* Oa  = Qf;               // alias: Qf dead after norm_kernel

    // 1) QKV GEMM: Q,K -> f32 (B,H,Nt,D); V -> bf16 transposed (B,H,D,Nt)
    dim3 g1((M1c + 127) / 128, N1c / 128);
    gemm_fp32<0><<<g1, 256, 0, stream>>>(X, S, Wqkv, Qf, Kf, Vtg, nullptr, M1c, N1c);

    // 2) normalize q,k; fold temperature; emit bf16
    norm_kernel<<<(Bc * Hc * NTc) / 4, 256, 0, stream>>>(Qf, Kf, Qbf, Kbf, temp);

    // 3) MFMA flash attention -> Oa (B,N,C) f32
    attn_mfma<<<Bc * Hc * QT128, 256, 0, stream>>>(Qbf, Kbf, Vtg, temp, Oa);

    // 4) output GEMM
    dim3 g2(M2c / 128, Cc / 128);
    gemm_fp32<1><<<g2, 256, 0, stream>>>(Oa, nullptr, Wout, nullptr, nullptr, nullptr, out, M2c, Cc);
}

// Round 4
// 306.540 us; speedup vs baseline: 5.0123x; 1.3643x over previous
//
#include <hip/hip_runtime.h>
#include <math.h>

typedef unsigned short u16;
typedef unsigned int   u32;
typedef __attribute__((ext_vector_type(8)))  __bf16 bf16x8;
typedef __attribute__((ext_vector_type(16))) float  f32x16;

constexpr int Bc  = 4;
constexpr int Nc  = 2304;
constexpr int KSc = 8;
constexpr int Cc  = 512;
constexpr int Hc  = 8;
constexpr int Dc  = 64;
constexpr int NTc = Nc + KSc;          // 2312
constexpr int M1c = Bc * NTc;          // 9248
constexpr int N1c = 3 * Cc;            // 1536
constexpr int M2c = Bc * Nc;           // 9216
constexpr int QT128 = Nc / 128;        // 18
constexpr int KT64  = NTc / 64;        // 36 full tiles (+8 tail)

__device__ __forceinline__ u32 f2bf1(float f) {
    u32 u = __float_as_uint(f);
    return (u + 0x7fffu + ((u >> 16) & 1u)) >> 16;   // RNE bf16
}
__device__ __forceinline__ u32 pk2(float lo, float hi) {
    u32 ul = __float_as_uint(lo);
    u32 uh = __float_as_uint(hi);
    ul = (ul + 0x7fffu + ((ul >> 16) & 1u)) >> 16;
    uh = (uh + 0x7fffu + ((uh >> 16) & 1u)) & 0xffff0000u;
    return ul | uh;
}
__device__ __forceinline__ float bf2f(u16 x) {
    return __uint_as_float(((u32)x) << 16);
}

#define MFMA32(A, B, C) __builtin_amdgcn_mfma_f32_32x32x16_bf16(A, B, C, 0, 0, 0)

union U4 { u32 u[4]; bf16x8 f; };
union KV8 { uint4 v; u16 u[8]; };

// ---------------------------------------------------------------------------
// concat(X,S) -> bf16 A [M1][512]
// ---------------------------------------------------------------------------
__global__ __launch_bounds__(256)
void cvt_concat(const float* __restrict__ X, const float* __restrict__ S,
                u16* __restrict__ A)
{
    const int id  = blockIdx.x * 256 + threadIdx.x;   // chunk of 8 elements
    const int row = id >> 6;
    const int ch  = (id & 63) * 8;
    const int b = row / NTc, t = row - b * NTc;
    const float* src = (t < Nc) ? X + ((size_t)(b * Nc + t)) * Cc + ch
                                : S + ((size_t)(b * KSc + (t - Nc))) * Cc + ch;
    const float4 v0 = ((const float4*)src)[0];
    const float4 v1 = ((const float4*)src)[1];
    u32 w[4];
    w[0] = pk2(v0.x, v0.y); w[1] = pk2(v0.z, v0.w);
    w[2] = pk2(v1.x, v1.y); w[3] = pk2(v1.z, v1.w);
    *(uint4*)(A + (size_t)row * Cc + ch) = *(const uint4*)w;
}

// ---------------------------------------------------------------------------
// Transpose-cast weights: W [512][Nn] f32 -> WT [Nn][512] bf16 (+ lo part)
// ---------------------------------------------------------------------------
template<bool LO>
__global__ __launch_bounds__(256)
void cvt_w(const float* __restrict__ W, int Nn,
           u16* __restrict__ WT, u16* __restrict__ WTl)
{
    __shared__ float Ws[64][68];
    const int n0 = blockIdx.x * 64, k0 = blockIdx.y * 64;
#pragma unroll
    for (int i = 0; i < 4; ++i) {
        const int c = i * 256 + threadIdx.x;          // 0..1023
        const int kr = c >> 4, nc = (c & 15) * 4;
        const float4 v = *(const float4*)(W + (size_t)(k0 + kr) * Nn + n0 + nc);
        Ws[kr][nc] = v.x; Ws[kr][nc+1] = v.y; Ws[kr][nc+2] = v.z; Ws[kr][nc+3] = v.w;
    }
    __syncthreads();
#pragma unroll
    for (int i = 0; i < 2; ++i) {
        const int c = i * 256 + threadIdx.x;          // 0..511
        const int n = c >> 3, kc = (c & 7) * 8;
        u32 wh[4], wl[4];
#pragma unroll
        for (int j = 0; j < 4; ++j) {
            const float a = Ws[kc + 2*j][n], bq = Ws[kc + 2*j + 1][n];
            const u32 ha = f2bf1(a), hb = f2bf1(bq);
            wh[j] = ha | (hb << 16);
            if constexpr (LO) {
                const float la = a  - __uint_as_float(ha << 16);
                const float lb = bq - __uint_as_float(hb << 16);
                wl[j] = pk2(la, lb);
            }
        }
        *(uint4*)(WT + (size_t)(n0 + n) * Cc + k0 + kc) = *(const uint4*)wh;
        if constexpr (LO)
            *(uint4*)(WTl + (size_t)(n0 + n) * Cc + k0 + kc) = *(const uint4*)wl;
    }
}

// ---------------------------------------------------------------------------
// V (B,H,Nt,D) bf16 -> Vt (B,H,D,Nt) bf16
// ---------------------------------------------------------------------------
__global__ __launch_bounds__(256)
void transpose_v(const u16* __restrict__ Vbf, u16* __restrict__ Vt)
{
    __shared__ u16 Vs[64][80];
    const int bh = blockIdx.x;
    const int t0 = blockIdx.y * 64;
    const u16* src = Vbf + (size_t)bh * NTc * Dc;
#pragma unroll
    for (int i = 0; i < 2; ++i) {
        const int c = i * 256 + threadIdx.x;          // 0..511
        const int tr = c >> 3, dc = (c & 7) * 8;
        int tg = t0 + tr; if (tg > NTc - 1) tg = NTc - 1;
        const uint4 v = *(const uint4*)(src + (size_t)tg * Dc + dc);
        *(uint4*)&Vs[tr][dc] = v;
    }
    __syncthreads();
#pragma unroll
    for (int i = 0; i < 2; ++i) {
        const int c = i * 256 + threadIdx.x;
        const int d = c >> 3, tch = (c & 7) * 8;
        if (t0 + tch + 7 <= NTc - 1) {
            u16 tmp[8];
#pragma unroll
            for (int j = 0; j < 8; ++j) tmp[j] = Vs[tch + j][d];
            *(uint4*)(Vt + ((size_t)bh * Dc + d) * NTc + t0 + tch) = *(const uint4*)tmp;
        }
    }
}

// ---------------------------------------------------------------------------
// QKV GEMM, bf16 MFMA: [M1,512] x [512,1536] ; B pre-transposed [n][k].
// 128x128 tile, BK=64, 4 waves (2x2 of 32x32 frags each). Epilogue scatters
// raw bf16 q,k,v into (B,H,Nt,D).
// ---------------------------------------------------------------------------
__global__ __launch_bounds__(256)
void gemm_qkv(const u16* __restrict__ A, const u16* __restrict__ Bw,
              u16* __restrict__ Qb, u16* __restrict__ Kb, u16* __restrict__ Vb)
{
    __shared__ __align__(16) u16 As[128 * 64];
    __shared__ __align__(16) u16 Bs[128 * 64];
    char* ldsA = (char*)As;
    char* ldsB = (char*)Bs;

    const int tid = threadIdx.x;
    const int wid = tid >> 6, lane = tid & 63, hi = lane >> 5, ln = lane & 31;
    const int wm = wid >> 1, wn = wid & 1;
    const int m0 = blockIdx.x * 128, n0 = blockIdx.y * 128;

    f32x16 acc[2][2];
#pragma unroll
    for (int i = 0; i < 2; ++i)
#pragma unroll
        for (int j = 0; j < 2; ++j)
#pragma unroll
            for (int r = 0; r < 16; ++r) acc[i][j][r] = 0.f;

    for (int k0 = 0; k0 < Cc; k0 += 64) {
        uint4 av[4], bv[4];
#pragma unroll
        for (int i = 0; i < 4; ++i) {
            const int c = i * 256 + tid, row = c >> 3, slot = c & 7;
            int mg = m0 + row; if (mg > M1c - 1) mg = M1c - 1;
            av[i] = *(const uint4*)(A  + (size_t)mg * Cc + k0 + slot * 8);
            bv[i] = *(const uint4*)(Bw + (size_t)(n0 + row) * Cc + k0 + slot * 8);
        }
        __syncthreads();
#pragma unroll
        for (int i = 0; i < 4; ++i) {
            const int c = i * 256 + tid, row = c >> 3, slot = c & 7;
            const int wb = row * 128 + ((slot ^ (row & 7)) << 4);
            *(uint4*)(ldsA + wb) = av[i];
            *(uint4*)(ldsB + wb) = bv[i];
        }
        __syncthreads();
#pragma unroll
        for (int ks = 0; ks < 4; ++ks) {
            bf16x8 af[2], bfr[2];
#pragma unroll
            for (int f = 0; f < 2; ++f) {
                const int mr = wm * 64 + f * 32 + ln;
                af[f]  = *(const bf16x8*)(ldsA + mr * 128 + (((ks * 2 + hi) ^ (mr & 7)) << 4));
                const int nr = wn * 64 + f * 32 + ln;
                bfr[f] = *(const bf16x8*)(ldsB + nr * 128 + (((ks * 2 + hi) ^ (nr & 7)) << 4));
            }
#pragma unroll
            for (int fm = 0; fm < 2; ++fm)
#pragma unroll
                for (int fn = 0; fn < 2; ++fn)
                    acc[fm][fn] = MFMA32(af[fm], bfr[fn], acc[fm][fn]);
        }
    }

#pragma unroll
    for (int fm = 0; fm < 2; ++fm)
#pragma unroll
        for (int fn = 0; fn < 2; ++fn) {
            const int ng = n0 + wn * 64 + fn * 32 + ln;
            const int which = ng >> 9, h = (ng >> 6) & 7, d = ng & 63;
            u16* base = (which == 0) ? Qb : ((which == 1) ? Kb : Vb);
#pragma unroll
            for (int r = 0; r < 16; ++r) {
                const int mg = m0 + wm * 64 + fm * 32 + (r & 3) + 8 * (r >> 2) + 4 * hi;
                if (mg < M1c) {
                    const int b = mg / NTc, t = mg - b * NTc;
                    base[((size_t)((b * Hc + h) * NTc + t)) * Dc + d] = (u16)f2bf1(acc[fm][fn][r]);
                }
            }
        }
}

// ---------------------------------------------------------------------------
// Out GEMM, split-bf16 3-pass: C = Ah*Bh + Al*Bh + Ah*Bl (f32 out).
// A = Oattn hi/lo [9216][512]; B = WoutT hi/lo [512 n][512 k].
// ---------------------------------------------------------------------------
__global__ __launch_bounds__(256)
void gemm_out(const u16* __restrict__ Ahg, const u16* __restrict__ Alg,
              const u16* __restrict__ Bhg, const u16* __restrict__ Blg,
              float* __restrict__ Out)
{
    __shared__ __align__(16) u16 LAh[128 * 64];
    __shared__ __align__(16) u16 LAl[128 * 64];
    __shared__ __align__(16) u16 LBh[128 * 64];
    __shared__ __align__(16) u16 LBl[128 * 64];
    char* pAh = (char*)LAh; char* pAl = (char*)LAl;
    char* pBh = (char*)LBh; char* pBl = (char*)LBl;

    const int tid = threadIdx.x;
    const int wid = tid >> 6, lane = tid & 63, hi = lane >> 5, ln = lane & 31;
    const int wm = wid >> 1, wn = wid & 1;
    const int m0 = blockIdx.x * 128, n0 = blockIdx.y * 128;

    f32x16 acc[2][2];
#pragma unroll
    for (int i = 0; i < 2; ++i)
#pragma unroll
        for (int j = 0; j < 2; ++j)
#pragma unroll
            for (int r = 0; r < 16; ++r) acc[i][j][r] = 0.f;

    for (int k0 = 0; k0 < Cc; k0 += 64) {
        uint4 ah[4], al[4], bh[4], bl[4];
#pragma unroll
        for (int i = 0; i < 4; ++i) {
            const int c = i * 256 + tid, row = c >> 3, slot = c & 7;
            const size_t ao = (size_t)(m0 + row) * Cc + k0 + slot * 8;
            const size_t bo = (size_t)(n0 + row) * Cc + k0 + slot * 8;
            ah[i] = *(const uint4*)(Ahg + ao);
            al[i] = *(const uint4*)(Alg + ao);
            bh[i] = *(const uint4*)(Bhg + bo);
            bl[i] = *(const uint4*)(Blg + bo);
        }
        __syncthreads();
#pragma unroll
        for (int i = 0; i < 4; ++i) {
            const int c = i * 256 + tid, row = c >> 3, slot = c & 7;
            const int wb = row * 128 + ((slot ^ (row & 7)) << 4);
            *(uint4*)(pAh + wb) = ah[i];
            *(uint4*)(pAl + wb) = al[i];
            *(uint4*)(pBh + wb) = bh[i];
            *(uint4*)(pBl + wb) = bl[i];
        }
        __syncthreads();
#pragma unroll
        for (int ks = 0; ks < 4; ++ks) {
            bf16x8 afh[2], afl[2], bfh[2], bfl[2];
#pragma unroll
            for (int f = 0; f < 2; ++f) {
                const int mr = wm * 64 + f * 32 + ln;
                const int moff = mr * 128 + (((ks * 2 + hi) ^ (mr & 7)) << 4);
                afh[f] = *(const bf16x8*)(pAh + moff);
                afl[f] = *(const bf16x8*)(pAl + moff);
                const int nr = wn * 64 + f * 32 + ln;
                const int noff = nr * 128 + (((ks * 2 + hi) ^ (nr & 7)) << 4);
                bfh[f] = *(const bf16x8*)(pBh + noff);
                bfl[f] = *(const bf16x8*)(pBl + noff);
            }
#pragma unroll
            for (int fm = 0; fm < 2; ++fm)
#pragma unroll
                for (int fn = 0; fn < 2; ++fn) {
                    acc[fm][fn] = MFMA32(afh[fm], bfh[fn], acc[fm][fn]);
                    acc[fm][fn] = MFMA32(afl[fm], bfh[fn], acc[fm][fn]);
                    acc[fm][fn] = MFMA32(afh[fm], bfl[fn], acc[fm][fn]);
                }
        }
    }

#pragma unroll
    for (int fm = 0; fm < 2; ++fm)
#pragma unroll
        for (int fn = 0; fn < 2; ++fn) {
            const int ng = n0 + wn * 64 + fn * 32 + ln;
#pragma unroll
            for (int r = 0; r < 16; ++r) {
                const int mg = m0 + wm * 64 + fm * 32 + (r & 3) + 8 * (r >> 2) + 4 * hi;
                Out[(size_t)mg * Cc + ng] = acc[fm][fn][r];
            }
        }
}

// ---------------------------------------------------------------------------
// MFMA flash attention with FUSED L2-norm: q,k arrive raw bf16.
// qn = temp[h]/||q|| per query (lane); kn = 1/||k|| per key, computed during
// K-tile staging into knl[64]. logit = s * qn * kn; shift by |temp|.
// Output: Oattn hi/lo bf16 (split for the out GEMM).
// ---------------------------------------------------------------------------
__global__ __launch_bounds__(256)
void attn_mfma(const u16* __restrict__ Qbf, const u16* __restrict__ Kbf,
               const u16* __restrict__ Vtg, const float* __restrict__ temp,
               u16* __restrict__ Oh, u16* __restrict__ Ol)
{
    __shared__ __align__(16) u16 ldsK[64 * 64];
    __shared__ __align__(16) u16 ldsV[64 * 64];
    __shared__ float knl[64];

    const int tid  = threadIdx.x;
    const int wid  = tid >> 6;
    const int lane = tid & 63;
    const int hi   = lane >> 5;
    const int ln   = lane & 31;
    const int bh   = blockIdx.x / QT128;
    const int qt   = blockIdx.x - bh * QT128;
    const int b    = bh >> 3, h = bh & 7;
    const int qbase = qt * 128 + wid * 32;
    const float tmp_h  = temp[h];
    const float mconst = fabsf(tmp_h);

    // Q fragments (raw bf16) + per-query norm factor
    const u16* Qrow = Qbf + ((size_t)bh * NTc + qbase + ln) * Dc;
    bf16x8 qf[4];
    float qs = 0.f;
#pragma unroll
    for (int ks = 0; ks < 4; ++ks) {
        U4 tmp;
        tmp.f = *(const bf16x8*)(Qrow + ks * 16 + hi * 8);
        qf[ks] = tmp.f;
#pragma unroll
        for (int j = 0; j < 4; ++j) {
            const float x0 = bf2f((u16)(tmp.u[j] & 0xffff));
            const float x1 = bf2f((u16)(tmp.u[j] >> 16));
            qs = fmaf(x0, x0, qs);
            qs = fmaf(x1, x1, qs);
        }
    }
    qs += __shfl_xor(qs, 32);
    const float qn = tmp_h / fmaxf(sqrtf(qs), 1e-12f);

    f32x16 o0, o1;
#pragma unroll
    for (int r = 0; r < 16; ++r) { o0[r] = 0.f; o1[r] = 0.f; }
    float rs = 0.f;

    const u16* Kbh = Kbf + (size_t)bh * NTc * Dc;
    const u16* Vbh = Vtg + (size_t)bh * Dc * NTc;

    const int sc  = tid & 7;       // 16B chunk
    const int sr0 = tid >> 3;      // 0..31
    char* ldsKc = (char*)ldsK;
    char* ldsVc = (char*)ldsV;
    const int slot = (sc << 4) ^ ((sr0 & 7) << 4);

    for (int kt = 0; kt <= KT64; ++kt) {
        const int  kb   = kt * 64;
        const bool tail = (kt == KT64);
        __syncthreads();
#pragma unroll
        for (int half = 0; half < 2; ++half) {
            const int r   = sr0 + half * 32;
            const int wof = (r << 7) + slot;
            int rK = kb + r;
            if (rK > NTc - 1) rK = NTc - 1;
            int cV = kb + sc * 8;
            if (cV > NTc - 8) cV = NTc - 8;
            KV8 kv; kv.v = *(const uint4*)(Kbh + (size_t)rK * Dc + sc * 8);
            const uint4 vv = *(const uint4*)(Vbh + (size_t)r * NTc + cV);
            *(uint4*)(ldsKc + wof) = kv.v;
            *(uint4*)(ldsVc + wof) = vv;
            float ss = 0.f;
#pragma unroll
            for (int j = 0; j < 8; ++j) {
                const float x = bf2f(kv.u[j]);
                ss = fmaf(x, x, ss);
            }
            ss += __shfl_xor(ss, 1);
            ss += __shfl_xor(ss, 2);
            ss += __shfl_xor(ss, 4);
            if (sc == 0) knl[r] = 1.0f / fmaxf(sqrtf(ss), 1e-12f);
        }
        __syncthreads();

        const int nsub = tail ? 1 : 2;
        for (int kt2 = 0; kt2 < nsub; ++kt2) {
            f32x16 s;
#pragma unroll
            for (int r = 0; r < 16; ++r) s[r] = 0.f;
            const int krow = kt2 * 32 + ln;
            const char* kbc = ldsKc + (krow << 7);
            const int   ksz = (krow & 7) << 4;
#pragma unroll
            for (int ks = 0; ks < 4; ++ks) {
                const bf16x8 kf = *(const bf16x8*)(kbc + (((ks << 5) + (hi << 4)) ^ ksz));
                s = MFMA32(kf, qf[ks], s);
            }

            float p[16];
            const int kyb = kt2 * 32;
#pragma unroll
            for (int r = 0; r < 16; ++r) {
                const int key = kyb + (r & 3) + 8 * (r >> 2) + 4 * hi;
                const float lg = s[r] * qn * knl[key];
                p[r] = __expf(lg - mconst);
            }
            if (tail) {
#pragma unroll
                for (int r = 4; r < 16; ++r) p[r] = 0.f;
            }
#pragma unroll
            for (int r = 0; r < 16; ++r) rs += p[r];

            const u32 a0 = pk2(p[0],  p[1]),  a1 = pk2(p[2],  p[3]);
            const u32 b0 = pk2(p[4],  p[5]),  b1 = pk2(p[6],  p[7]);
            const u32 c0 = pk2(p[8],  p[9]),  c1 = pk2(p[10], p[11]);
            const u32 d0 = pk2(p[12], p[13]), d1 = pk2(p[14], p[15]);
            const u32 xa0 = (u32)__shfl_xor((int)a0, 32);
            const u32 xa1 = (u32)__shfl_xor((int)a1, 32);
            const u32 xb0 = (u32)__shfl_xor((int)b0, 32);
            const u32 xb1 = (u32)__shfl_xor((int)b1, 32);
            const u32 xc0 = (u32)__shfl_xor((int)c0, 32);
            const u32 xc1 = (u32)__shfl_xor((int)c1, 32);
            const u32 xd0 = (u32)__shfl_xor((int)d0, 32);
            const u32 xd1 = (u32)__shfl_xor((int)d1, 32);
            U4 f0, f1;
            f0.u[0] = hi ? xb0 : a0;
            f0.u[1] = hi ? xb1 : a1;
            f0.u[2] = hi ? b0  : xa0;
            f0.u[3] = hi ? b1  : xa1;
            f1.u[0] = hi ? xd0 : c0;
            f1.u[1] = hi ? xd1 : c1;
            f1.u[2] = hi ? d0  : xc0;
            f1.u[3] = hi ? d1  : xc1;

            const char* v0c = ldsVc + (ln << 7);
            const char* v1c = ldsVc + ((32 + ln) << 7);
            const int   vsz0 = (ln & 7) << 4;
            const int   cof0 = ((kt2 << 6) + (hi << 4)) ^ vsz0;
            const int   cof1 = ((kt2 << 6) + 32 + (hi << 4)) ^ vsz0;
            o0 = MFMA32(*(const bf16x8*)(v0c + cof0), f0.f, o0);
            o1 = MFMA32(*(const bf16x8*)(v1c + cof0), f0.f, o1);
            if (!tail) {
                o0 = MFMA32(*(const bf16x8*)(v0c + cof1), f1.f, o0);
                o1 = MFMA32(*(const bf16x8*)(v1c + cof1), f1.f, o1);
            }
        }
    }

    rs += __shfl_xor(rs, 32);
    const float inv = 1.0f / rs;
    const size_t orow = (size_t)(b * Nc) + qbase + ln;
    u16* Oph = Oh + orow * Cc + h * Dc;
    u16* Opl = Ol + orow * Cc + h * Dc;
#pragma unroll
    for (int g = 0; g < 4; ++g) {
#pragma unroll
        for (int sel = 0; sel < 2; ++sel) {
            const float x0 = (sel ? o1[4*g]   : o0[4*g])   * inv;
            const float x1 = (sel ? o1[4*g+1] : o0[4*g+1]) * inv;
            const float x2 = (sel ? o1[4*g+2] : o0[4*g+2]) * inv;
            const float x3 = (sel ? o1[4*g+3] : o0[4*g+3]) * inv;
            const u32 h0 = f2bf1(x0), h1 = f2bf1(x1), h2 = f2bf1(x2), h3 = f2bf1(x3);
            uint2 hv, lv;
            hv.x = h0 | (h1 << 16);
            hv.y = h2 | (h3 << 16);
            lv.x = pk2(x0 - __uint_as_float(h0 << 16), x1 - __uint_as_float(h1 << 16));
            lv.y = pk2(x2 - __uint_as_float(h2 << 16), x3 - __uint_as_float(h3 << 16));
            const int doff = sel * 32 + 8 * g + 4 * hi;
            *(uint2*)(Oph + doff) = hv;
            *(uint2*)(Opl + doff) = lv;
        }
    }
}

// ---------------------------------------------------------------------------
extern "C" void kernel_launch(void* const* d_in, const int* in_sizes, int n_in,
                              void* d_out, int out_size, void* d_ws, size_t ws_size,
                              hipStream_t stream)
{
    const float* X    = (const float*)d_in[0];
    const float* S    = (const float*)d_in[1];
    const float* Wqkv = (const float*)d_in[2];
    const float* Wout = (const float*)d_in[3];
    const float* temp = (const float*)d_in[4];
    float* out = (float*)d_out;

    u16* ws16 = (u16*)d_ws;
    const size_t R = (size_t)Bc * Hc * NTc * Dc;      // 4,734,976 (== M1c*Cc)
    u16* Abf  = ws16;
    u16* WqT  = Abf  + (size_t)M1c * Cc;
    u16* WoTh = WqT  + (size_t)N1c * Cc;
    u16* WoTl = WoTh + (size_t)Cc * Cc;
    u16* Qbf  = WoTl + (size_t)Cc * Cc;
    u16* Kbf  = Qbf + R;
    u16* Vbf  = Kbf + R;
    u16* Vt   = Vbf + R;
    u16* Oh   = Vt  + R;
    u16* Ol   = Oh  + (size_t)M2c * Cc;

    // 1) input concat + bf16 cast
    cvt_concat<<<M1c * (Cc / 8) / 256, 256, 0, stream>>>(X, S, Abf);
    // 2) weight transpose-casts
    cvt_w<false><<<dim3(N1c / 64, Cc / 64), 256, 0, stream>>>(Wqkv, N1c, WqT, nullptr);
    cvt_w<true ><<<dim3(Cc  / 64, Cc / 64), 256, 0, stream>>>(Wout, Cc,  WoTh, WoTl);
    // 3) QKV GEMM (bf16 MFMA) -> raw bf16 q,k,v in (B,H,Nt,D)
    gemm_qkv<<<dim3((M1c + 127) / 128, N1c / 128), 256, 0, stream>>>(Abf, WqT, Qbf, Kbf, Vbf);
    // 4) V transpose -> (B,H,D,Nt)
    transpose_v<<<dim3(Bc * Hc, (NTc + 63) / 64), 256, 0, stream>>>(Vbf, Vt);
    // 5) attention with fused norm -> Oattn hi/lo
    attn_mfma<<<Bc * Hc * QT128, 256, 0, stream>>>(Qbf, Kbf, Vt, temp, Oh, Ol);
    // 6) out GEMM (split-bf16 3-pass) -> f32 out
    gemm_out<<<dim3(M2c / 128, Cc / 128), 256, 0, stream>>>(Oh, Ol, WoTh, WoTl, out);
}